// Round 1
// baseline (400.692 us; speedup 1.0000x reference)
//
#include <hip/hip_runtime.h>
#include <hip/hip_bf16.h>

#define LOG2E 1.4426950408889634f

typedef __attribute__((ext_vector_type(8))) short frag_ab;   // 8 bf16 (4 VGPRs)
typedef __attribute__((ext_vector_type(4))) float frag_cd;   // 4 fp32 acc

// fp32 -> bf16 bits, round-to-nearest-even (inputs finite)
__device__ inline short f2bf(float f) {
    union { float f; unsigned u; } v; v.f = f;
    unsigned r = v.u + 0x7fffu + ((v.u >> 16) & 1u);
    return (short)(r >> 16);
}

// rmm[h] = log2e * max_k cov[h,k]; rmm[128+h] = log2e * min_k cov[h,k]
__global__ __launch_bounds__(128) void prep_kernel(const float* __restrict__ cov,
                                                   float* __restrict__ rmm) {
    int h = threadIdx.x;
    float mx = -1e30f, mn = 1e30f;
    for (int k = 0; k < 128; ++k) {
        float c = cov[h * 128 + k];
        mx = fmaxf(mx, c);
        mn = fminf(mn, c);
    }
    rmm[h] = LOG2E * mx;
    rmm[128 + h] = LOG2E * mn;
}

// vm[row][h] = sum_k x[row][k] * W[h][k]   (row = 2b -> values, 2b+1 -> mask)
// One wave computes 16 rows x 128 h via 8 MFMA tiles (16x16x32 bf16).
__global__ __launch_bounds__(256) void proj_kernel(const float* __restrict__ x,
                                                   const float* __restrict__ W,
                                                   float* __restrict__ vm) {
    const int lane = threadIdx.x & 63;
    const int wave = threadIdx.x >> 6;
    const int m = lane & 15;       // A row within tile / B col (=h) within tile
    const int kg = lane >> 4;      // k-group 0..3; k = kg*8 + j
    const long rowbase = ((long)blockIdx.x * 4 + wave) * 16;

    frag_cd acc[8];
#pragma unroll
    for (int t = 0; t < 8; ++t) acc[t] = (frag_cd){0.f, 0.f, 0.f, 0.f};

    const float* xrow = x + (rowbase + m) * 1024 + kg * 8;

    for (int kb = 0; kb < 1024; kb += 32) {
        float4 a0 = *(const float4*)(xrow + kb);
        float4 a1 = *(const float4*)(xrow + kb + 4);
        frag_ab af;
        af[0] = f2bf(a0.x); af[1] = f2bf(a0.y); af[2] = f2bf(a0.z); af[3] = f2bf(a0.w);
        af[4] = f2bf(a1.x); af[5] = f2bf(a1.y); af[6] = f2bf(a1.z); af[7] = f2bf(a1.w);
#pragma unroll
        for (int t = 0; t < 8; ++t) {
            const float* wrow = W + (long)(t * 16 + m) * 1024 + kb + kg * 8;
            float4 b0 = *(const float4*)(wrow);
            float4 b1 = *(const float4*)(wrow + 4);
            frag_ab bf;
            bf[0] = f2bf(b0.x); bf[1] = f2bf(b0.y); bf[2] = f2bf(b0.z); bf[3] = f2bf(b0.w);
            bf[4] = f2bf(b1.x); bf[5] = f2bf(b1.y); bf[6] = f2bf(b1.z); bf[7] = f2bf(b1.w);
            acc[t] = __builtin_amdgcn_mfma_f32_16x16x32_bf16(af, bf, acc[t], 0, 0, 0);
        }
    }
    // C/D layout: col = lane&15, row = (lane>>4)*4 + reg
#pragma unroll
    for (int t = 0; t < 8; ++t) {
#pragma unroll
        for (int r = 0; r < 4; ++r) {
            long row = rowbase + kg * 4 + r;
            vm[row * 128 + t * 16 + m] = acc[t][r];
        }
    }
}

// out[b,k] = bias[k] + sum_h (values[b,h]/l[b,h]) * exp2(mask[b,h]*cov2[h,k] - m2[b,h])
// Thread (i,j): h in [8i,8i+8), k in [8j,8j+8). cov2 = log2e*cov held in 64 regs,
// p tile held in 64 regs -> exp computed exactly once per element.
__global__ __launch_bounds__(256) void combine_kernel(const float* __restrict__ vm,
                                                      const float* __restrict__ cov,
                                                      const float* __restrict__ bias,
                                                      const float* __restrict__ rmm,
                                                      float* __restrict__ out, int B) {
    __shared__ float mask_s[128], m2_s[128], w_s[128], v_s[128];
    __shared__ float lbuf[128][17];
    __shared__ float obuf[128][17];
    const int t = threadIdx.x;
    const int i = t >> 4;   // h-group
    const int j = t & 15;   // k-group

    float covreg[8][8];
#pragma unroll
    for (int hh = 0; hh < 8; ++hh) {
        const float* cr = cov + (long)(i * 8 + hh) * 128 + j * 8;
        float4 c0 = *(const float4*)cr;
        float4 c1 = *(const float4*)(cr + 4);
        covreg[hh][0] = LOG2E * c0.x; covreg[hh][1] = LOG2E * c0.y;
        covreg[hh][2] = LOG2E * c0.z; covreg[hh][3] = LOG2E * c0.w;
        covreg[hh][4] = LOG2E * c1.x; covreg[hh][5] = LOG2E * c1.y;
        covreg[hh][6] = LOG2E * c1.z; covreg[hh][7] = LOG2E * c1.w;
    }
    float rmax_own = 0.f, rmin_own = 0.f, bias_own = 0.f;
    if (t < 128) {
        rmax_own = rmm[t];
        rmin_own = rmm[128 + t];
        bias_own = bias[t];
    }

    for (int b = blockIdx.x; b < B; b += gridDim.x) {
        if (t < 128) {
            float val = vm[(long)(2 * b) * 128 + t];
            float mk  = vm[(long)(2 * b + 1) * 128 + t];
            v_s[t] = val;
            mask_s[t] = mk;
            m2_s[t] = mk * (mk >= 0.f ? rmax_own : rmin_own);
        }
        __syncthreads();

        float p[8][8];
#pragma unroll
        for (int hh = 0; hh < 8; ++hh) {
            float mh = mask_s[i * 8 + hh];
            float mm = m2_s[i * 8 + hh];
            float lsum = 0.f;
#pragma unroll
            for (int kk = 0; kk < 8; ++kk) {
                float e = __builtin_amdgcn_exp2f(fmaf(mh, covreg[hh][kk], -mm));
                p[hh][kk] = e;
                lsum += e;
            }
            lbuf[i * 8 + hh][j] = lsum;
        }
        __syncthreads();

        if (t < 128) {
            float l = 0.f;
#pragma unroll
            for (int jj = 0; jj < 16; ++jj) l += lbuf[t][jj];
            w_s[t] = v_s[t] / l;
        }
        __syncthreads();

        float op[8] = {0.f, 0.f, 0.f, 0.f, 0.f, 0.f, 0.f, 0.f};
#pragma unroll
        for (int hh = 0; hh < 8; ++hh) {
            float wv = w_s[i * 8 + hh];
#pragma unroll
            for (int kk = 0; kk < 8; ++kk) op[kk] = fmaf(wv, p[hh][kk], op[kk]);
        }
#pragma unroll
        for (int kk = 0; kk < 8; ++kk) obuf[j * 8 + kk][i] = op[kk];
        __syncthreads();

        if (t < 128) {
            float o = 0.f;
#pragma unroll
            for (int ii = 0; ii < 16; ++ii) o += obuf[t][ii];
            out[(long)b * 128 + t] = o + bias_own;
        }
        __syncthreads();
    }
}

extern "C" void kernel_launch(void* const* d_in, const int* in_sizes, int n_in,
                              void* d_out, int out_size, void* d_ws, size_t ws_size,
                              hipStream_t stream) {
    const float* x    = (const float*)d_in[0];
    const float* W    = (const float*)d_in[1];
    const float* cov  = (const float*)d_in[2];
    const float* bias = (const float*)d_in[3];
    float* out = (float*)d_out;

    const int B = in_sizes[0] / (2 * 1024);   // 16384

    float* vm  = (float*)d_ws;                      // [2B][128]
    float* rmm = vm + (size_t)2 * B * 128;          // [256]

    prep_kernel<<<1, 128, 0, stream>>>(cov, rmm);

    const int rows = 2 * B;                   // 32768
    const int blocks = rows / (16 * 4);       // 16 rows/wave, 4 waves/block
    proj_kernel<<<blocks, 256, 0, stream>>>(x, W, vm);

    combine_kernel<<<2048, 256, 0, stream>>>(vm, cov, bias, rmm, out, B);
}

// Round 2
// 270.613 us; speedup vs baseline: 1.4807x; 1.4807x over previous
//
#include <hip/hip_runtime.h>
#include <hip/hip_bf16.h>

#define LOG2E 1.4426950408889634f

typedef __attribute__((ext_vector_type(8))) short frag_ab;   // 8 bf16 (4 VGPRs)
typedef __attribute__((ext_vector_type(4))) float frag_cd;   // 4 fp32 acc

// fp32 -> bf16 bits, round-to-nearest-even (inputs finite)
__device__ inline short f2bf(float f) {
    union { float f; unsigned u; } v; v.f = f;
    unsigned r = v.u + 0x7fffu + ((v.u >> 16) & 1u);
    return (short)(r >> 16);
}

// Blocks 0..63: convert W[128][1024] fp32 -> wbf bf16 in MFMA *fragment order*:
//   element (h,k): chunk c=k>>6, kstep s=(k>>5)&1, kg=(k>>3)&3, j=k&7,
//   ntile nt=h>>4, m=h&15, lane=kg*16+m
//   wbf[ (((c*8+nt)*2+s)*64 + lane)*8 + j ]
// Blocks 64..191: rmm[h] = log2e*max_k cov[h,:], rmm[128+h] = log2e*min_k.
__global__ __launch_bounds__(256) void prep_kernel(const float* __restrict__ W,
                                                   const float* __restrict__ cov,
                                                   short* __restrict__ wbf,
                                                   float* __restrict__ rmm) {
    if (blockIdx.x < 64) {
        int g = blockIdx.x * 256 + threadIdx.x;   // 0..16383
        int h = g >> 7;
        int k0 = (g & 127) << 3;
        const float* src = W + h * 1024 + k0;
        float4 w0 = *(const float4*)src;
        float4 w1 = *(const float4*)(src + 4);
        frag_ab af;
        af[0] = f2bf(w0.x); af[1] = f2bf(w0.y); af[2] = f2bf(w0.z); af[3] = f2bf(w0.w);
        af[4] = f2bf(w1.x); af[5] = f2bf(w1.y); af[6] = f2bf(w1.z); af[7] = f2bf(w1.w);
        int c = k0 >> 6, s = (k0 >> 5) & 1, kg = (k0 >> 3) & 3;
        int nt = h >> 4, m = h & 15, lane = kg * 16 + m;
        int dst = (((c * 8 + nt) * 2 + s) * 64 + lane) * 8;
        *(frag_ab*)(wbf + dst) = af;
    } else {
        int h = blockIdx.x - 64;
        int lane = threadIdx.x;
        if (lane < 64) {
            float c1 = cov[h * 128 + lane];
            float c2 = cov[h * 128 + 64 + lane];
            float mx = fmaxf(c1, c2), mn = fminf(c1, c2);
            for (int o = 1; o < 64; o <<= 1) {
                mx = fmaxf(mx, __shfl_xor(mx, o, 64));
                mn = fminf(mn, __shfl_xor(mn, o, 64));
            }
            if (lane == 0) { rmm[h] = LOG2E * mx; rmm[128 + h] = LOG2E * mn; }
        }
    }
}

// vm[row][h] = sum_k x[row][k]*W[h][k].  Block: 64 rows, N=128, K chunks of 64.
// B (Wbf) staged global->LDS in fragment order (contiguous), double-buffered.
// A fragments loaded direct from global (each byte read once), prefetched.
__global__ __launch_bounds__(256, 2) void proj_kernel(const float* __restrict__ x,
                                                      const short* __restrict__ wbf,
                                                      float* __restrict__ vm) {
    __shared__ __align__(16) short Bs[2][8192];   // 16 KB per buffer
    const int tid = threadIdx.x;
    const int lane = tid & 63, wave = tid >> 6;
    const int m = lane & 15, kg = lane >> 4;
    const long rowbase = (long)blockIdx.x * 64 + wave * 16;
    const float* xrow = x + (rowbase + m) * 1024 + kg * 8;

    frag_cd acc[8];
#pragma unroll
    for (int nt = 0; nt < 8; ++nt) acc[nt] = (frag_cd){0.f, 0.f, 0.f, 0.f};

    // stage B chunk 0
    {
        const char* wc = (const char*)wbf;
        float4 t0 = *(const float4*)(wc + tid * 16);
        float4 t1 = *(const float4*)(wc + 4096 + tid * 16);
        float4 t2 = *(const float4*)(wc + 8192 + tid * 16);
        float4 t3 = *(const float4*)(wc + 12288 + tid * 16);
        char* bd = (char*)&Bs[0][0] + tid * 16;
        *(float4*)(bd)         = t0;
        *(float4*)(bd + 4096)  = t1;
        *(float4*)(bd + 8192)  = t2;
        *(float4*)(bd + 12288) = t3;
    }
    // prefetch A chunk 0
    float4 a0 = *(const float4*)(xrow);
    float4 a1 = *(const float4*)(xrow + 4);
    float4 a2 = *(const float4*)(xrow + 32);
    float4 a3 = *(const float4*)(xrow + 36);
    __syncthreads();

    int cb = 0;
    for (int c = 0; c < 16; ++c) {
        // next-chunk prefetch (global, lands during compute)
        float4 n0, n1, n2, n3, B0, B1, B2, B3;
        if (c < 15) {
            const float* xn = xrow + (c + 1) * 64;
            n0 = *(const float4*)(xn);
            n1 = *(const float4*)(xn + 4);
            n2 = *(const float4*)(xn + 32);
            n3 = *(const float4*)(xn + 36);
            const char* wc = (const char*)wbf + (c + 1) * 16384;
            B0 = *(const float4*)(wc + tid * 16);
            B1 = *(const float4*)(wc + 4096 + tid * 16);
            B2 = *(const float4*)(wc + 8192 + tid * 16);
            B3 = *(const float4*)(wc + 12288 + tid * 16);
        }
        // A fragments for this chunk
        frag_ab af0, af1;
        af0[0] = f2bf(a0.x); af0[1] = f2bf(a0.y); af0[2] = f2bf(a0.z); af0[3] = f2bf(a0.w);
        af0[4] = f2bf(a1.x); af0[5] = f2bf(a1.y); af0[6] = f2bf(a1.z); af0[7] = f2bf(a1.w);
        af1[0] = f2bf(a2.x); af1[1] = f2bf(a2.y); af1[2] = f2bf(a2.z); af1[3] = f2bf(a2.w);
        af1[4] = f2bf(a3.x); af1[5] = f2bf(a3.y); af1[6] = f2bf(a3.z); af1[7] = f2bf(a3.w);

        const char* bs = (const char*)&Bs[cb][0];
#pragma unroll
        for (int nt = 0; nt < 8; ++nt) {
            frag_ab bf0 = *(const frag_ab*)(bs + (nt * 2 + 0) * 1024 + lane * 16);
            acc[nt] = __builtin_amdgcn_mfma_f32_16x16x32_bf16(af0, bf0, acc[nt], 0, 0, 0);
            frag_ab bf1 = *(const frag_ab*)(bs + (nt * 2 + 1) * 1024 + lane * 16);
            acc[nt] = __builtin_amdgcn_mfma_f32_16x16x32_bf16(af1, bf1, acc[nt], 0, 0, 0);
        }
        if (c < 15) {
            char* bd = (char*)&Bs[cb ^ 1][0] + tid * 16;
            *(float4*)(bd)         = B0;
            *(float4*)(bd + 4096)  = B1;
            *(float4*)(bd + 8192)  = B2;
            *(float4*)(bd + 12288) = B3;
            a0 = n0; a1 = n1; a2 = n2; a3 = n3;
        }
        __syncthreads();
        cb ^= 1;
    }

    // C/D: col = lane&15 (=h within tile), row = kg*4 + r
#pragma unroll
    for (int nt = 0; nt < 8; ++nt) {
#pragma unroll
        for (int r = 0; r < 4; ++r) {
            long row = rowbase + kg * 4 + r;
            vm[row * 128 + nt * 16 + m] = acc[nt][r];
        }
    }
}

// out[b,k] = bias[k] + sum_h (v[b,h]/l[b,h]) * exp2(mask[b,h]*cov2[h,k] - m2[b,h])
// 512 threads: thread (i=t>>4, j=t&15) owns h in [4i,4i+4), k in [8j,8j+8).
// k-reduction (l) via 16-lane shfl butterfly (no LDS, no barrier);
// h-reduction via obuf LDS. 2 barriers per b.
__global__ __launch_bounds__(512, 4) void combine_kernel(const float* __restrict__ vm,
                                                         const float* __restrict__ cov,
                                                         const float* __restrict__ bias,
                                                         const float* __restrict__ rmm,
                                                         float* __restrict__ out, int B) {
    __shared__ float mask_s[128], m2_s[128], v_s[128];
    __shared__ float obuf[32][132];
    const int t = threadIdx.x;
    const int i = t >> 4;   // h-group 0..31
    const int j = t & 15;   // k-group 0..15

    float covreg[4][8];
#pragma unroll
    for (int hh = 0; hh < 4; ++hh) {
        const float* cr = cov + (long)(i * 4 + hh) * 128 + j * 8;
        float4 c0 = *(const float4*)cr;
        float4 c1 = *(const float4*)(cr + 4);
        covreg[hh][0] = LOG2E * c0.x; covreg[hh][1] = LOG2E * c0.y;
        covreg[hh][2] = LOG2E * c0.z; covreg[hh][3] = LOG2E * c0.w;
        covreg[hh][4] = LOG2E * c1.x; covreg[hh][5] = LOG2E * c1.y;
        covreg[hh][6] = LOG2E * c1.z; covreg[hh][7] = LOG2E * c1.w;
    }
    float rmax_own = 0.f, rmin_own = 0.f, bias_own = 0.f;
    if (t < 128) {
        rmax_own = rmm[t];
        rmin_own = rmm[128 + t];
        bias_own = bias[t];
    }

    for (int b = blockIdx.x; b < B; b += gridDim.x) {
        if (t < 128) {
            float val = vm[(long)(2 * b) * 128 + t];
            float mk  = vm[(long)(2 * b + 1) * 128 + t];
            v_s[t] = val;
            mask_s[t] = mk;
            m2_s[t] = mk * (mk >= 0.f ? rmax_own : rmin_own);
        }
        __syncthreads();

        float op[8] = {0.f, 0.f, 0.f, 0.f, 0.f, 0.f, 0.f, 0.f};
#pragma unroll
        for (int hh = 0; hh < 4; ++hh) {
            float mh = mask_s[i * 4 + hh];
            float mm = m2_s[i * 4 + hh];
            float p[8];
            float lsum = 0.f;
#pragma unroll
            for (int kk = 0; kk < 8; ++kk) {
                float e = __builtin_amdgcn_exp2f(fmaf(mh, covreg[hh][kk], -mm));
                p[kk] = e;
                lsum += e;
            }
            // butterfly sum over the 16-lane j-group: all lanes get full l[h]
            lsum += __shfl_xor(lsum, 1, 16);
            lsum += __shfl_xor(lsum, 2, 16);
            lsum += __shfl_xor(lsum, 4, 16);
            lsum += __shfl_xor(lsum, 8, 16);
            float w = v_s[i * 4 + hh] * __builtin_amdgcn_rcpf(lsum);
#pragma unroll
            for (int kk = 0; kk < 8; ++kk) op[kk] = fmaf(w, p[kk], op[kk]);
        }
        *(float4*)&obuf[i][j * 8]     = make_float4(op[0], op[1], op[2], op[3]);
        *(float4*)&obuf[i][j * 8 + 4] = make_float4(op[4], op[5], op[6], op[7]);
        __syncthreads();

        if (t < 128) {
            float o = 0.f;
#pragma unroll
            for (int ii = 0; ii < 32; ++ii) o += obuf[ii][t];
            out[(long)b * 128 + t] = o + bias_own;
        }
        __syncthreads();
    }
}

extern "C" void kernel_launch(void* const* d_in, const int* in_sizes, int n_in,
                              void* d_out, int out_size, void* d_ws, size_t ws_size,
                              hipStream_t stream) {
    const float* x    = (const float*)d_in[0];
    const float* W    = (const float*)d_in[1];
    const float* cov  = (const float*)d_in[2];
    const float* bias = (const float*)d_in[3];
    float* out = (float*)d_out;

    const int B = in_sizes[0] / (2 * 1024);   // 16384

    float* vm  = (float*)d_ws;                          // [2B][128] fp32
    short* wbf = (short*)(vm + (size_t)2 * B * 128);    // [128*1024] bf16, frag order
    float* rmm = (float*)(wbf + 128 * 1024);            // [256]

    prep_kernel<<<192, 256, 0, stream>>>(W, cov, wbf, rmm);

    const int blocks = (2 * B) / 64;          // 64 rows per block -> 512
    proj_kernel<<<blocks, 256, 0, stream>>>(x, wbf, vm);

    combine_kernel<<<2048, 512, 0, stream>>>(vm, cov, bias, rmm, out, B);
}